// Round 9
// baseline (648.746 us; speedup 1.0000x reference)
//
#include <hip/hip_runtime.h>
#include <hip/hip_bf16.h>
#include <hip/hip_cooperative_groups.h>
#include <stdint.h>

// Problem constants (K=4, OUT=4096, IN=4096, B=2, S=2048)
#define DIM_M 4096   // B*S rows of x
#define DIM_N 4096   // OUT
#define DIM_K 4096   // IN
#define BASE_STRIDE (DIM_N * DIM_K)  // elements per basis
#define NT (DIM_K / 64)              // 64 K-tiles of BK=64

typedef __bf16 bf16x8 __attribute__((ext_vector_type(8)));
typedef float floatx4 __attribute__((ext_vector_type(4)));
typedef unsigned short ushort8 __attribute__((ext_vector_type(8)));

__device__ __forceinline__ unsigned short f2bf(float f) {
    uint32_t u = __float_as_uint(f);
    uint32_t r = (u + 0x7FFFu + ((u >> 16) & 1u)) >> 16;  // RNE
    return (unsigned short)r;
}

// ---------------------------------------------------------------------------
// Prep work bodies (identical math to the verified prep_kernel, re-indexed).
// W: Wb = bf16(sum_k alpha_k * bases_k); X: Xb = bf16(x). 8 elems per unit.
// ---------------------------------------------------------------------------
__device__ __forceinline__ void prep_w_unit(long e,
        const int* __restrict__ bases, float a0, float a1, float a2, float a3,
        unsigned short* __restrict__ Wb) {
    const int4 p0 = *(const int4*)(bases + e);
    const int4 p1 = *(const int4*)(bases + e + 4);
    const int4 q0 = *(const int4*)(bases + BASE_STRIDE + e);
    const int4 q1 = *(const int4*)(bases + BASE_STRIDE + e + 4);
    const int4 r0 = *(const int4*)(bases + 2L * BASE_STRIDE + e);
    const int4 r1 = *(const int4*)(bases + 2L * BASE_STRIDE + e + 4);
    const int4 s0 = *(const int4*)(bases + 3L * BASE_STRIDE + e);
    const int4 s1 = *(const int4*)(bases + 3L * BASE_STRIDE + e + 4);
    ushort8 o;
    o[0] = f2bf(a0 * p0.x + a1 * q0.x + a2 * r0.x + a3 * s0.x);
    o[1] = f2bf(a0 * p0.y + a1 * q0.y + a2 * r0.y + a3 * s0.y);
    o[2] = f2bf(a0 * p0.z + a1 * q0.z + a2 * r0.z + a3 * s0.z);
    o[3] = f2bf(a0 * p0.w + a1 * q0.w + a2 * r0.w + a3 * s0.w);
    o[4] = f2bf(a0 * p1.x + a1 * q1.x + a2 * r1.x + a3 * s1.x);
    o[5] = f2bf(a0 * p1.y + a1 * q1.y + a2 * r1.y + a3 * s1.y);
    o[6] = f2bf(a0 * p1.z + a1 * q1.z + a2 * r1.z + a3 * s1.z);
    o[7] = f2bf(a0 * p1.w + a1 * q1.w + a2 * r1.w + a3 * s1.w);
    *(ushort8*)(Wb + e) = o;
}

__device__ __forceinline__ void prep_x_unit(long e,
        const float* __restrict__ x, unsigned short* __restrict__ Xb) {
    const float4 v0 = *(const float4*)(x + e);
    const float4 v1 = *(const float4*)(x + e + 4);
    ushort8 o;
    o[0] = f2bf(v0.x); o[1] = f2bf(v0.y); o[2] = f2bf(v0.z); o[3] = f2bf(v0.w);
    o[4] = f2bf(v1.x); o[5] = f2bf(v1.y); o[6] = f2bf(v1.z); o[7] = f2bf(v1.w);
    *(ushort8*)(Xb + e) = o;
}

// ---------------------------------------------------------------------------
// Standalone prep kernel (fallback path; identical to verified version).
// ---------------------------------------------------------------------------
__global__ __launch_bounds__(256) void prep_kernel(
        const int* __restrict__ bases, const float* __restrict__ alphas,
        const float* __restrict__ x,
        unsigned short* __restrict__ Wb, unsigned short* __restrict__ Xb) {
    const int bid = blockIdx.x;
    const float a0 = alphas[0], a1 = alphas[1], a2 = alphas[2], a3 = alphas[3];
    if (bid < 8192) {
        const long e = ((long)bid * 256 + threadIdx.x) * 8;
        prep_w_unit(e, bases, a0, a1, a2, a3, Wb);
    } else {
        const long e = ((long)(bid - 8192) * 256 + threadIdx.x) * 8;
        prep_x_unit(e, x, Xb);
    }
}

// ---------------------------------------------------------------------------
// GEMM body, 256x256 tile / BK=64 / 8-wave / 16x16x32 MFMA + T1 XCD swizzle.
// Byte-identical logic to R8 (best, 526.6us total / ~124us gemm), refactored
// into a __device__ function so the cooperative fused kernel and the
// standalone fallback kernel share it.
//
// R7 schedule: every ds_read lands one phase before consumption:
//   P1: [reads B2-3]; stage A1(t+1); Q00 MFMA (frags from prev P4); BAR
//   P2: Q01 MFMA; [reads A4-7 post-cluster]; BAR
//   P3: stage B0(t+2); Q11 MFMA; BAR
//   P4: stage B1,A0(t+2); vmcnt(6); BAR; Q10 MFMA; [boundary reads]; BAR
// vmcnt ledger (verified): tile t halves issue B0@(t-2)P3, B1@(t-2)P4,
// A0@(t-2)P4, A1@(t-1)P1; at (t-1)P4 post-stage: 14 outstanding; vmcnt(6)
// retires the 8 oldest = tile t. Prologue 14 loads + vmcnt(6). Last iter
// vmcnt(0), group B skips boundary reads. WAR: every region's last ds_read
// drains >=1 barrier before its restage.
// LDS: [buf][A,B][half][128x64] = 128 KiB; global_load_lds w16 linear dest;
// chunk^(row&7) pre-swizzled source; read-side XOR (uniform 8 dwords/bank =
// b128 floor; st_16x32 port was analyzed and would CONCENTRATE our reads
// onto 4/8 chunks -> kept our swizzle). 16x16x32 layouts (HW-verified):
// A/B m(/n)=lane&15, k=(lane>>4)*8+j; C/D col=lane&15, row=(lane>>4)*4+reg.
// T1 remap (bijective, 256 = 8 XCD x 32): xcd=lin&7, idx=lin>>3,
// by=(xcd>>1)*4+(idx>>3), bx=(xcd&1)*8+(idx&7).
// ---------------------------------------------------------------------------
#define MFMA16 __builtin_amdgcn_mfma_f32_16x16x32_bf16
#define BAR()   __builtin_amdgcn_s_barrier()
#define PRIO1() __builtin_amdgcn_s_setprio(1)
#define PRIO0() __builtin_amdgcn_s_setprio(0)

__device__ __forceinline__ void stage_half(const unsigned short* __restrict__ gb,
        int grow0, int kbase, unsigned short* ld, int wave, int lane) {
#pragma unroll
    for (int r = 0; r < 2; ++r) {
        const int row = wave * 16 + r * 8 + (lane >> 3);       // local row in half
        const int ch  = (lane & 7) ^ (row & 7);                // pre-swizzled src chunk
        const unsigned short* g = gb + (size_t)(grow0 + row) * DIM_K + kbase + ch * 8;
        unsigned short* d = ld + (wave * 16 + r * 8) * 64;     // wave-uniform LDS base
        __builtin_amdgcn_global_load_lds(
            (const __attribute__((address_space(1))) unsigned int*)((const void*)g),
            (__attribute__((address_space(3))) unsigned int*)((void*)d), 16, 0, 0);
    }
}

#define DS_A16(LD, MF, SLOT)                                                          \
    do {                                                                              \
        aR[SLOT][0] = *(const bf16x8*)((LD) + ((MF) * 16 + l15) * 64 + cko2[0]);      \
        aR[SLOT][1] = *(const bf16x8*)((LD) + ((MF) * 16 + l15) * 64 + cko2[1]);      \
    } while (0)
#define DS_B16(LD, NF, SLOT)                                                          \
    do {                                                                              \
        bR[SLOT][0] = *(const bf16x8*)((LD) + (nloc + (NF) * 16 + l15) * 64 + cko2[0]); \
        bR[SLOT][1] = *(const bf16x8*)((LD) + (nloc + (NF) * 16 + l15) * 64 + cko2[1]); \
    } while (0)
#define MMQ(MB, NB)                                                                   \
    do { _Pragma("unroll") for (int kh = 0; kh < 2; ++kh)                             \
        _Pragma("unroll") for (int n = 0; n < 2; ++n)                                 \
            _Pragma("unroll") for (int m = 0; m < 4; ++m)                             \
                acc4[(MB) + m][(NB) + n] = MFMA16(aR[m][kh], bR[(NB) + n][kh],        \
                                                  acc4[(MB) + m][(NB) + n], 0, 0, 0); \
    } while (0)

// LDS half offsets (elements): lds[b][op][h] -> ((b*2+op)*2+h)*8192
#define L000 0
#define L001 8192
#define L010 16384
#define L011 24576
#define L100 32768
#define L101 40960
#define L110 49152
#define L111 57344

__device__ __forceinline__ void gemm_body(
        const unsigned short* __restrict__ A, const unsigned short* __restrict__ Bt,
        float* __restrict__ C, unsigned short* ldsb, int lin, int t) {
    const int wave = t >> 6, lane = t & 63;
    const int l15 = lane & 15, l4 = lane >> 4;     // 16x16 frag coords
    const int wm = wave >> 2;            // 0..1  -> A half / row block of 128
    const int wn = wave & 3;             // 0..3  -> 64-col block
    const int nloc = (wn & 1) * 64;      // row offset inside B half (wn>>1)

    const int xcd = lin & 7, idx = lin >> 3;
    const int by = (xcd >> 1) * 4 + (idx >> 3);
    const int bx = (xcd & 1) * 8 + (idx & 7);
    const int mBase = by * 256;
    const int nBase = bx * 256;

    const unsigned short* LA0 = ldsb + (wm ? L001 : L000);
    const unsigned short* LA1 = ldsb + (wm ? L101 : L100);
    const unsigned short* LB0 = ldsb + ((wn >> 1) ? L011 : L010);
    const unsigned short* LB1 = ldsb + ((wn >> 1) ? L111 : L110);

    int cko2[2];
#pragma unroll
    for (int kh = 0; kh < 2; ++kh) cko2[kh] = ((l4 + 4 * kh) ^ (l15 & 7)) * 8;

    floatx4 acc4[8][4] = {};
    bf16x8 aR[4][2], bR[4][2];

    // ---- prologue: tile0 -> buf0 (all 4 halves); tile1 -> buf1 (B0,B1,A0) ----
    stage_half(A,  mBase + 0,   0,  ldsb + L000, wave, lane);
    stage_half(A,  mBase + 128, 0,  ldsb + L001, wave, lane);
    stage_half(Bt, nBase + 0,   0,  ldsb + L010, wave, lane);
    stage_half(Bt, nBase + 128, 0,  ldsb + L011, wave, lane);
    stage_half(Bt, nBase + 0,   64, ldsb + L110, wave, lane);
    stage_half(Bt, nBase + 128, 64, ldsb + L111, wave, lane);
    stage_half(A,  mBase + 0,   64, ldsb + L100, wave, lane);
    asm volatile("s_waitcnt vmcnt(6)" ::: "memory");   // tile0 fully landed
    BAR();
    DS_A16(LA0, 0, 0); DS_A16(LA0, 1, 1); DS_A16(LA0, 2, 2); DS_A16(LA0, 3, 3);
    DS_B16(LB0, 0, 0); DS_B16(LB0, 1, 1);

    for (int i = 0; i < NT / 2; ++i) {
        const bool more = (i < NT / 2 - 1);
        const int t1k = (2 * i + 1) * 64;
        const int t2k = (2 * i + 2) * 64;
        const int t3k = (2 * i + 3) * 64;

        // ================= group A: tile 2i from buf0 =================
        DS_B16(LB0, 2, 2); DS_B16(LB0, 3, 3);
        stage_half(A, mBase + 128, t1k, ldsb + L101, wave, lane);   // A1(t+1)
        PRIO1(); MMQ(0, 0); PRIO0();
        BAR();
        PRIO1(); MMQ(0, 2); PRIO0();
        DS_A16(LA0, 4, 0); DS_A16(LA0, 5, 1); DS_A16(LA0, 6, 2); DS_A16(LA0, 7, 3);
        BAR();
        if (more) stage_half(Bt, nBase + 0, t2k, ldsb + L010, wave, lane);
        PRIO1(); MMQ(4, 2); PRIO0();
        BAR();
        if (more) {
            stage_half(Bt, nBase + 128, t2k, ldsb + L011, wave, lane);
            stage_half(A,  mBase + 0,   t2k, ldsb + L000, wave, lane);
            asm volatile("s_waitcnt vmcnt(6)" ::: "memory");
        } else {
            asm volatile("s_waitcnt vmcnt(0)" ::: "memory");
        }
        BAR();
        PRIO1(); MMQ(4, 0); PRIO0();
        DS_A16(LA1, 0, 0); DS_A16(LA1, 1, 1); DS_A16(LA1, 2, 2); DS_A16(LA1, 3, 3);
        DS_B16(LB1, 0, 0); DS_B16(LB1, 1, 1);
        BAR();

        // ================= group B: tile 2i+1 from buf1 =================
        DS_B16(LB1, 2, 2); DS_B16(LB1, 3, 3);
        if (more) stage_half(A, mBase + 128, t2k, ldsb + L001, wave, lane); // A1(t+2)
        PRIO1(); MMQ(0, 0); PRIO0();
        BAR();
        PRIO1(); MMQ(0, 2); PRIO0();
        DS_A16(LA1, 4, 0); DS_A16(LA1, 5, 1); DS_A16(LA1, 6, 2); DS_A16(LA1, 7, 3);
        BAR();
        if (more) stage_half(Bt, nBase + 0, t3k, ldsb + L110, wave, lane);
        PRIO1(); MMQ(4, 2); PRIO0();
        BAR();
        if (more) {
            stage_half(Bt, nBase + 128, t3k, ldsb + L111, wave, lane);
            stage_half(A,  mBase + 0,   t3k, ldsb + L100, wave, lane);
            asm volatile("s_waitcnt vmcnt(6)" ::: "memory");
        } else {
            asm volatile("s_waitcnt vmcnt(0)" ::: "memory");
        }
        BAR();
        PRIO1(); MMQ(4, 0); PRIO0();
        if (more) {
            DS_A16(LA0, 0, 0); DS_A16(LA0, 1, 1); DS_A16(LA0, 2, 2); DS_A16(LA0, 3, 3);
            DS_B16(LB0, 0, 0); DS_B16(LB0, 1, 1);
        }
        BAR();
    }

    // Epilogue: 16x16 C/D layout col=lane&15, row=(lane>>4)*4+reg
#pragma unroll
    for (int mf = 0; mf < 8; ++mf) {
#pragma unroll
        for (int nf = 0; nf < 4; ++nf) {
#pragma unroll
            for (int r = 0; r < 4; ++r) {
                const int row = mBase + wm * 128 + mf * 16 + l4 * 4 + r;
                const int col = nBase + wn * 64 + nf * 16 + l15;
                C[(size_t)row * DIM_N + col] = acc4[mf][nf][r];
            }
        }
    }
}

// Standalone GEMM kernel (fallback path) — identical to R8.
__global__ __launch_bounds__(512, 2) void gemm_bt_kernel(
        const unsigned short* __restrict__ A, const unsigned short* __restrict__ Bt,
        float* __restrict__ C) {
    __shared__ __align__(16) unsigned short lds[2][2][2][128 * 64];  // 128 KiB
    const int lin = blockIdx.y * gridDim.x + blockIdx.x;
    gemm_body(A, Bt, C, &lds[0][0][0][0], lin, (int)threadIdx.x);
}

// ---------------------------------------------------------------------------
// R9: Fused cooperative kernel — prep (grid-stride over 256x512 threads) +
// grid.sync + gemm. Saves the prep-kernel launch + inter-kernel gap (~10-20us
// of the 526us total). Prep at 2 waves/SIMD still saturates HBM: 8 16B-loads
// in flight per wave x 16 waves/CU = 2KB outstanding/CU >> 10.8 B/cyc/CU
// needed at the 400MB/63us roofline. Co-residency: 256 blocks x 1 block/CU
// (128KB LDS) = exact fit. Fallback: hipLaunchCooperativeKernel returns its
// error synchronously -> two-kernel R8 path, byte-identical behavior.
// ---------------------------------------------------------------------------
__global__ __launch_bounds__(512, 2) void fused_kernel(
        const int* __restrict__ bases, const float* __restrict__ alphas,
        const float* __restrict__ x,
        unsigned short* __restrict__ Wb, unsigned short* __restrict__ Xb,
        float* __restrict__ C) {
    __shared__ __align__(16) unsigned short lds[2][2][2][128 * 64];  // 128 KiB

    const int gtid = (int)blockIdx.x * 512 + (int)threadIdx.x;  // 0..131071
    {
        const float a0 = alphas[0], a1 = alphas[1], a2 = alphas[2], a3 = alphas[3];
#pragma unroll 1
        for (int u = 0; u < 16; ++u) {           // 16 x 131072 x 8 = 16.78M W elems
            const long e = ((long)(u * 131072 + gtid)) * 8;
            prep_w_unit(e, bases, a0, a1, a2, a3, Wb);
        }
#pragma unroll 1
        for (int u = 0; u < 16; ++u) {           // 16.78M X elems
            const long e = ((long)(u * 131072 + gtid)) * 8;
            prep_x_unit(e, x, Xb);
        }
    }
    __threadfence();                              // device-scope visibility
    cooperative_groups::this_grid().sync();       // all Wb/Xb written

    gemm_body(Xb, Wb, C, &lds[0][0][0][0], (int)blockIdx.x, (int)threadIdx.x);
}

// ---------------------------------------------------------------------------
// Fallback (only if workspace too small): direct fp32, one thread per output
// ---------------------------------------------------------------------------
__global__ __launch_bounds__(256) void naive_kernel(
        const float* __restrict__ x, const float* __restrict__ alphas,
        const int* __restrict__ bases, float* __restrict__ out) {
    const long o = (long)blockIdx.x * 256 + threadIdx.x;
    const int m = (int)(o >> 12), n = (int)(o & 4095);
    const float a0 = alphas[0], a1 = alphas[1], a2 = alphas[2], a3 = alphas[3];
    const float* xr = x + (long)m * DIM_K;
    const int* b0 = bases + (long)n * DIM_K;
    const int* b1 = b0 + BASE_STRIDE;
    const int* b2 = b1 + BASE_STRIDE;
    const int* b3 = b2 + BASE_STRIDE;
    float acc = 0.f;
    for (int i = 0; i < DIM_K; i++) {
        float w = a0 * b0[i] + a1 * b1[i] + a2 * b2[i] + a3 * b3[i];
        acc += xr[i] * w;
    }
    out[o] = acc;
}

extern "C" void kernel_launch(void* const* d_in, const int* in_sizes, int n_in,
                              void* d_out, int out_size, void* d_ws, size_t ws_size,
                              hipStream_t stream) {
    const float* x      = (const float*)d_in[0];
    const float* alphas = (const float*)d_in[1];
    const int*   bases  = (const int*)d_in[2];
    float* out = (float*)d_out;

    const size_t need = (size_t)2 * DIM_N * DIM_K + (size_t)2 * DIM_M * DIM_K; // 64 MB
    if (ws_size >= need) {
        unsigned short* Wb = (unsigned short*)d_ws;                    // [4096][4096] bf16
        unsigned short* Xb = (unsigned short*)d_ws + (size_t)DIM_N * DIM_K;

        // Try the fused cooperative path (saves one launch + gap).
        const int* b_ = bases; const float* al_ = alphas; const float* x_ = x;
        unsigned short* wb_ = Wb; unsigned short* xb_ = Xb; float* c_ = out;
        void* args[] = {(void*)&b_, (void*)&al_, (void*)&x_,
                        (void*)&wb_, (void*)&xb_, (void*)&c_};
        hipError_t rc = hipLaunchCooperativeKernel(
            reinterpret_cast<void*>(fused_kernel), dim3(256), dim3(512),
            args, 0, stream);
        if (rc != hipSuccess) {
            // Fallback: verified two-kernel R8 path.
            prep_kernel<<<16384, 256, 0, stream>>>(bases, alphas, x, Wb, Xb);
            gemm_bt_kernel<<<dim3(DIM_N / 256, DIM_M / 256), 512, 0, stream>>>(Xb, Wb, out);
        }
    } else {
        naive_kernel<<<(DIM_M * DIM_N) / 256, 256, 0, stream>>>(x, alphas, bases, out);
    }
}

// Round 10
// 528.431 us; speedup vs baseline: 1.2277x; 1.2277x over previous
//
#include <hip/hip_runtime.h>
#include <hip/hip_bf16.h>
#include <stdint.h>

// Problem constants (K=4, OUT=4096, IN=4096, B=2, S=2048)
#define DIM_M 4096   // B*S rows of x
#define DIM_N 4096   // OUT
#define DIM_K 4096   // IN
#define BASE_STRIDE (DIM_N * DIM_K)  // elements per basis
#define NT (DIM_K / 64)              // 64 K-tiles of BK=64

typedef __bf16 bf16x8 __attribute__((ext_vector_type(8)));
typedef float floatx4 __attribute__((ext_vector_type(4)));
typedef unsigned short ushort8 __attribute__((ext_vector_type(8)));

__device__ __forceinline__ unsigned short f2bf(float f) {
    uint32_t u = __float_as_uint(f);
    uint32_t r = (u + 0x7FFFu + ((u >> 16) & 1u)) >> 16;  // RNE
    return (unsigned short)r;
}

// ---------------------------------------------------------------------------
// Fused prologue (verified): blocks [0,8192) build W_bf16; [8192,16384)
// convert x fp32 -> bf16. 8 elems/thread, 16B stores. Standalone launch at
// 256 threads/block -> ~8 blocks/CU occupancy saturates HBM (R9 lesson:
// fusing this into the 1-block/CU gemm starves it to 1.2 TB/s by Little's
// law: 2KB in flight/CU / 900cy ~= 1.4 TB/s).
// ---------------------------------------------------------------------------
__global__ __launch_bounds__(256) void prep_kernel(
        const int* __restrict__ bases, const float* __restrict__ alphas,
        const float* __restrict__ x,
        unsigned short* __restrict__ Wb, unsigned short* __restrict__ Xb) {
    const int bid = blockIdx.x;
    if (bid < 8192) {
        const long e = ((long)bid * 256 + threadIdx.x) * 8;
        const float a0 = alphas[0], a1 = alphas[1], a2 = alphas[2], a3 = alphas[3];
        const int4 p0 = *(const int4*)(bases + e);
        const int4 p1 = *(const int4*)(bases + e + 4);
        const int4 q0 = *(const int4*)(bases + BASE_STRIDE + e);
        const int4 q1 = *(const int4*)(bases + BASE_STRIDE + e + 4);
        const int4 r0 = *(const int4*)(bases + 2L * BASE_STRIDE + e);
        const int4 r1 = *(const int4*)(bases + 2L * BASE_STRIDE + e + 4);
        const int4 s0 = *(const int4*)(bases + 3L * BASE_STRIDE + e);
        const int4 s1 = *(const int4*)(bases + 3L * BASE_STRIDE + e + 4);
        ushort8 o;
        o[0] = f2bf(a0 * p0.x + a1 * q0.x + a2 * r0.x + a3 * s0.x);
        o[1] = f2bf(a0 * p0.y + a1 * q0.y + a2 * r0.y + a3 * s0.y);
        o[2] = f2bf(a0 * p0.z + a1 * q0.z + a2 * r0.z + a3 * s0.z);
        o[3] = f2bf(a0 * p0.w + a1 * q0.w + a2 * r0.w + a3 * s0.w);
        o[4] = f2bf(a0 * p1.x + a1 * q1.x + a2 * r1.x + a3 * s1.x);
        o[5] = f2bf(a0 * p1.y + a1 * q1.y + a2 * r1.y + a3 * s1.y);
        o[6] = f2bf(a0 * p1.z + a1 * q1.z + a2 * r1.z + a3 * s1.z);
        o[7] = f2bf(a0 * p1.w + a1 * q1.w + a2 * r1.w + a3 * s1.w);
        *(ushort8*)(Wb + e) = o;
    } else {
        const long e = ((long)(bid - 8192) * 256 + threadIdx.x) * 8;
        const float4 v0 = *(const float4*)(x + e);
        const float4 v1 = *(const float4*)(x + e + 4);
        ushort8 o;
        o[0] = f2bf(v0.x); o[1] = f2bf(v0.y); o[2] = f2bf(v0.z); o[3] = f2bf(v0.w);
        o[4] = f2bf(v1.x); o[5] = f2bf(v1.y); o[6] = f2bf(v1.z); o[7] = f2bf(v1.w);
        *(ushort8*)(Xb + e) = o;
    }
}

// ---------------------------------------------------------------------------
// Main GEMM, 256x256 tile / BK=64 / 8-wave / 16x16x32 MFMA + T1 XCD swizzle.
// Best measured configuration (R8: 526.6us total / ~124us gemm, ~1080 TF).
//
// R7 schedule: every ds_read lands one phase before consumption:
//   P1: [reads B2-3]; stage A1(t+1); Q00 MFMA (frags from prev P4); BAR
//   P2: Q01 MFMA; [reads A4-7 post-cluster]; BAR
//   P3: stage B0(t+2); Q11 MFMA; BAR
//   P4: stage B1,A0(t+2); vmcnt(6); BAR; Q10 MFMA; [boundary reads]; BAR
// vmcnt ledger (verified): tile t halves issue B0@(t-2)P3, B1@(t-2)P4,
// A0@(t-2)P4, A1@(t-1)P1; at (t-1)P4 post-stage: 14 outstanding; vmcnt(6)
// retires the 8 oldest = tile t. Prologue 14 loads + vmcnt(6). Last iter
// vmcnt(0), group B skips boundary reads. WAR: every region's last ds_read
// drains >=1 barrier before its restage.
//
// LDS: [buf][A,B][half][128x64] = 128 KiB; global_load_lds w16 linear dest;
// chunk^(row&7) pre-swizzled source; read-side XOR (uniform 8 dwords/bank).
// 16x16x32 layouts (HW-verified): A/B m(/n)=lane&15, k=(lane>>4)*8+j;
// C/D col=lane&15, row=(lane>>4)*4+reg.
// T1 remap (bijective, 256 = 8 XCD x 32): xcd=lin&7, idx=lin>>3,
// by=(xcd>>1)*4+(idx>>3), bx=(xcd&1)*8+(idx&7).
//
// Session plateau notes (R3-R9): read placement (12/4/8/0 vs 16/0/8/0 vs
// cross-phase) neutral; 4-phase merge -7%; a[4] slots spill (acc=128 regs
// -> 2 waves/SIMD is a hard reg ceiling, 4 waves/SIMD infeasible at 256^2);
// XCD swizzle +0.5%; coop-fused prep -23% (occupancy starvation). The
// gemm's 4650 cyc/K-tile ~= LDS-read 2300 + MFMA 2060 serialized is
// structural at this occupancy.
// ---------------------------------------------------------------------------
#define MFMA16 __builtin_amdgcn_mfma_f32_16x16x32_bf16
#define BAR()   __builtin_amdgcn_s_barrier()
#define PRIO1() __builtin_amdgcn_s_setprio(1)
#define PRIO0() __builtin_amdgcn_s_setprio(0)

__device__ __forceinline__ void stage_half(const unsigned short* __restrict__ gb,
        int grow0, int kbase, unsigned short* ld, int wave, int lane) {
#pragma unroll
    for (int r = 0; r < 2; ++r) {
        const int row = wave * 16 + r * 8 + (lane >> 3);       // local row in half
        const int ch  = (lane & 7) ^ (row & 7);                // pre-swizzled src chunk
        const unsigned short* g = gb + (size_t)(grow0 + row) * DIM_K + kbase + ch * 8;
        unsigned short* d = ld + (wave * 16 + r * 8) * 64;     // wave-uniform LDS base
        __builtin_amdgcn_global_load_lds(
            (const __attribute__((address_space(1))) unsigned int*)((const void*)g),
            (__attribute__((address_space(3))) unsigned int*)((void*)d), 16, 0, 0);
    }
}

// Load one 16-row fragment pair (both k-halves) for A (row base MF*16)
#define DS_A16(LD, MF, SLOT)                                                          \
    do {                                                                              \
        aR[SLOT][0] = *(const bf16x8*)((LD) + ((MF) * 16 + l15) * 64 + cko2[0]);      \
        aR[SLOT][1] = *(const bf16x8*)((LD) + ((MF) * 16 + l15) * 64 + cko2[1]);      \
    } while (0)
// and for B (row base nloc + NF*16)
#define DS_B16(LD, NF, SLOT)                                                          \
    do {                                                                              \
        bR[SLOT][0] = *(const bf16x8*)((LD) + (nloc + (NF) * 16 + l15) * 64 + cko2[0]); \
        bR[SLOT][1] = *(const bf16x8*)((LD) + (nloc + (NF) * 16 + l15) * 64 + cko2[1]); \
    } while (0)
// One C-quadrant x K=64: 16 MFMA, kh-outer (dep distance 8 per acc chain)
#define MMQ(MB, NB)                                                                   \
    do { _Pragma("unroll") for (int kh = 0; kh < 2; ++kh)                             \
        _Pragma("unroll") for (int n = 0; n < 2; ++n)                                 \
            _Pragma("unroll") for (int m = 0; m < 4; ++m)                             \
                acc4[(MB) + m][(NB) + n] = MFMA16(aR[m][kh], bR[(NB) + n][kh],        \
                                                  acc4[(MB) + m][(NB) + n], 0, 0, 0); \
    } while (0)

__global__ __launch_bounds__(512, 2) void gemm_bt_kernel(
        const unsigned short* __restrict__ A, const unsigned short* __restrict__ Bt,
        float* __restrict__ C) {
    __shared__ __align__(16) unsigned short lds[2][2][2][128 * 64];  // 128 KiB

    const int t = threadIdx.x;
    const int wave = t >> 6, lane = t & 63;
    const int l15 = lane & 15, l4 = lane >> 4;     // 16x16 frag coords
    const int wm = wave >> 2;            // 0..1  -> A half / row block of 128
    const int wn = wave & 3;             // 0..3  -> 64-col block
    const int nloc = (wn & 1) * 64;      // row offset inside B half (wn>>1)

    // T1: XCD-aware remap (bijective, 256 = 8 XCD x 32). Dispatch order is
    // linear (x fastest); lin%8 = XCD (m09). Each XCD owns a 4(y) x 8(x)
    // contiguous tile region.
    const int lin = blockIdx.y * gridDim.x + blockIdx.x;
    const int xcd = lin & 7, idx = lin >> 3;
    const int by = (xcd >> 1) * 4 + (idx >> 3);
    const int bx = (xcd & 1) * 8 + (idx & 7);
    const int mBase = by * 256;
    const int nBase = bx * 256;

    const unsigned short* LA0 = &lds[0][0][wm][0];
    const unsigned short* LA1 = &lds[1][0][wm][0];
    const unsigned short* LB0 = &lds[0][1][wn >> 1][0];
    const unsigned short* LB1 = &lds[1][1][wn >> 1][0];

    int cko2[2];
#pragma unroll
    for (int kh = 0; kh < 2; ++kh) cko2[kh] = ((l4 + 4 * kh) ^ (l15 & 7)) * 8;

    floatx4 acc4[8][4] = {};
    bf16x8 aR[4][2], bR[4][2];

    // ---- prologue: tile0 -> buf0 (all 4 halves); tile1 -> buf1 (B0,B1,A0) ----
    stage_half(A,  mBase + 0,   0,  &lds[0][0][0][0], wave, lane);
    stage_half(A,  mBase + 128, 0,  &lds[0][0][1][0], wave, lane);
    stage_half(Bt, nBase + 0,   0,  &lds[0][1][0][0], wave, lane);
    stage_half(Bt, nBase + 128, 0,  &lds[0][1][1][0], wave, lane);
    stage_half(Bt, nBase + 0,   64, &lds[1][1][0][0], wave, lane);
    stage_half(Bt, nBase + 128, 64, &lds[1][1][1][0], wave, lane);
    stage_half(A,  mBase + 0,   64, &lds[1][0][0][0], wave, lane);
    asm volatile("s_waitcnt vmcnt(6)" ::: "memory");   // tile0 fully landed
    BAR();
    // boundary reads for tile0's Q00 (consumed in first PA1)
    DS_A16(LA0, 0, 0); DS_A16(LA0, 1, 1); DS_A16(LA0, 2, 2); DS_A16(LA0, 3, 3);
    DS_B16(LB0, 0, 0); DS_B16(LB0, 1, 1);

    for (int i = 0; i < NT / 2; ++i) {
        const bool more = (i < NT / 2 - 1);
        const int t1k = (2 * i + 1) * 64;
        const int t2k = (2 * i + 2) * 64;
        const int t3k = (2 * i + 3) * 64;

        // ================= group A: tile 2i from buf0 =================
        // P1: Q00 (frags pre-read at prev P4-end); pre-read B2-3 (free slots)
        DS_B16(LB0, 2, 2); DS_B16(LB0, 3, 3);
        stage_half(A, mBase + 128, t1k, &lds[1][0][1][0], wave, lane);   // A1(t+1)
        PRIO1(); MMQ(0, 0); PRIO0();
        BAR();
        // P2: Q01 (b2-3 landed under P1); post-read A4-7 into freed a0-3
        PRIO1(); MMQ(0, 2); PRIO0();
        DS_A16(LA0, 4, 0); DS_A16(LA0, 5, 1); DS_A16(LA0, 6, 2); DS_A16(LA0, 7, 3);
        BAR();
        // P3: Q11 (A4-7 landed under P2/barrier)
        if (more) stage_half(Bt, nBase + 0, t2k, &lds[0][1][0][0], wave, lane);
        PRIO1(); MMQ(4, 2); PRIO0();
        BAR();
        // P4: stage; vmcnt; mid-BAR (RAW for buf1); Q10; boundary reads (buf1)
        if (more) {
            stage_half(Bt, nBase + 128, t2k, &lds[0][1][1][0], wave, lane);
            stage_half(A,  mBase + 0,   t2k, &lds[0][0][0][0], wave, lane);
            asm volatile("s_waitcnt vmcnt(6)" ::: "memory");
        } else {
            asm volatile("s_waitcnt vmcnt(0)" ::: "memory");
        }
        BAR();
        PRIO1(); MMQ(4, 0); PRIO0();
        DS_A16(LA1, 0, 0); DS_A16(LA1, 1, 1); DS_A16(LA1, 2, 2); DS_A16(LA1, 3, 3);
        DS_B16(LB1, 0, 0); DS_B16(LB1, 1, 1);
        BAR();

        // ================= group B: tile 2i+1 from buf1 =================
        // P1
        DS_B16(LB1, 2, 2); DS_B16(LB1, 3, 3);
        if (more) stage_half(A, mBase + 128, t2k, &lds[0][0][1][0], wave, lane); // A1(t+2)
        PRIO1(); MMQ(0, 0); PRIO0();
        BAR();
        // P2
        PRIO1(); MMQ(0, 2); PRIO0();
        DS_A16(LA1, 4, 0); DS_A16(LA1, 5, 1); DS_A16(LA1, 6, 2); DS_A16(LA1, 7, 3);
        BAR();
        // P3
        if (more) stage_half(Bt, nBase + 0, t3k, &lds[1][1][0][0], wave, lane);
        PRIO1(); MMQ(4, 2); PRIO0();
        BAR();
        // P4
        if (more) {
            stage_half(Bt, nBase + 128, t3k, &lds[1][1][1][0], wave, lane);
            stage_half(A,  mBase + 0,   t3k, &lds[1][0][0][0], wave, lane);
            asm volatile("s_waitcnt vmcnt(6)" ::: "memory");
        } else {
            asm volatile("s_waitcnt vmcnt(0)" ::: "memory");
        }
        BAR();
        PRIO1(); MMQ(4, 0); PRIO0();
        if (more) {
            DS_A16(LA0, 0, 0); DS_A16(LA0, 1, 1); DS_A16(LA0, 2, 2); DS_A16(LA0, 3, 3);
            DS_B16(LB0, 0, 0); DS_B16(LB0, 1, 1);
        }
        BAR();
    }

    // Epilogue: 16x16 C/D layout col=lane&15, row=(lane>>4)*4+reg
#pragma unroll
    for (int mf = 0; mf < 8; ++mf) {
#pragma unroll
        for (int nf = 0; nf < 4; ++nf) {
#pragma unroll
            for (int r = 0; r < 4; ++r) {
                const int row = mBase + wm * 128 + mf * 16 + l4 * 4 + r;
                const int col = nBase + wn * 64 + nf * 16 + l15;
                C[(size_t)row * DIM_N + col] = acc4[mf][nf][r];
            }
        }
    }
}

// ---------------------------------------------------------------------------
// Fallback (only if workspace too small): direct fp32, one thread per output
// ---------------------------------------------------------------------------
__global__ __launch_bounds__(256) void naive_kernel(
        const float* __restrict__ x, const float* __restrict__ alphas,
        const int* __restrict__ bases, float* __restrict__ out) {
    const long o = (long)blockIdx.x * 256 + threadIdx.x;
    const int m = (int)(o >> 12), n = (int)(o & 4095);
    const float a0 = alphas[0], a1 = alphas[1], a2 = alphas[2], a3 = alphas[3];
    const float* xr = x + (long)m * DIM_K;
    const int* b0 = bases + (long)n * DIM_K;
    const int* b1 = b0 + BASE_STRIDE;
    const int* b2 = b1 + BASE_STRIDE;
    const int* b3 = b2 + BASE_STRIDE;
    float acc = 0.f;
    for (int i = 0; i < DIM_K; i++) {
        float w = a0 * b0[i] + a1 * b1[i] + a2 * b2[i] + a3 * b3[i];
        acc += xr[i] * w;
    }
    out[o] = acc;
}

extern "C" void kernel_launch(void* const* d_in, const int* in_sizes, int n_in,
                              void* d_out, int out_size, void* d_ws, size_t ws_size,
                              hipStream_t stream) {
    const float* x      = (const float*)d_in[0];
    const float* alphas = (const float*)d_in[1];
    const int*   bases  = (const int*)d_in[2];
    float* out = (float*)d_out;

    const size_t need = (size_t)2 * DIM_N * DIM_K + (size_t)2 * DIM_M * DIM_K; // 64 MB
    if (ws_size >= need) {
        unsigned short* Wb = (unsigned short*)d_ws;                    // [4096][4096] bf16
        unsigned short* Xb = (unsigned short*)d_ws + (size_t)DIM_N * DIM_K;
        prep_kernel<<<16384, 256, 0, stream>>>(bases, alphas, x, Wb, Xb);
        gemm_bt_kernel<<<dim3(DIM_N / 256, DIM_M / 256), 512, 0, stream>>>(Xb, Wb, out);
    } else {
        naive_kernel<<<(DIM_M * DIM_N) / 256, 256, 0, stream>>>(x, alphas, bases, out);
    }
}